// Round 1
// baseline (120.364 us; speedup 1.0000x reference)
//
#include <hip/hip_runtime.h>
#include <math.h>

#define B_ 16
#define T_ 256
#define NTR_ 1024
#define NTE_ 256
#define K1_ 16

__global__ __launch_bounds__(256) void decoder_kernel(
    const float* __restrict__ z0,        // (B,T,1)
    const float* __restrict__ z1,        // (B,T,2)
    const float* __restrict__ coeff0,    // (1,1)
    const float* __restrict__ mean0,     // (1,1,1)
    const float* __restrict__ log_var0,  // (1,1,1)
    const float* __restrict__ coeff1,    // (1,16)
    const float* __restrict__ mean1,     // (1,16,2)
    const float* __restrict__ log_var1,  // (1,16,2)
    const float* __restrict__ rf_tr0,    // (NTR,1)
    const float* __restrict__ rf_tr1,    // (NTR,2)
    const float* __restrict__ rf_te0,    // (NTE,1)
    const float* __restrict__ rf_te1,    // (NTE,2)
    const float* __restrict__ ew_tr,     // (NTR,2)
    const float* __restrict__ ew_te,     // (NTE,2)
    const float* __restrict__ lfs_tr,    // (NTR,)
    const float* __restrict__ lfs_te,    // (NTE,)
    float* __restrict__ out)             // out_tr (B,NTR,T) ++ out_te (B,NTE,T)
{
    int bid = blockIdx.x;
    int t = threadIdx.x;

    // Select train vs test ensemble (wave-uniform branch)
    const float *rf0, *rf1, *ew, *lfs;
    float* obase;
    int N, lbid;
    if (bid < B_ * NTR_) {
        rf0 = rf_tr0; rf1 = rf_tr1; ew = ew_tr; lfs = lfs_tr;
        obase = out;
        N = NTR_; lbid = bid;
    } else {
        rf0 = rf_te0; rf1 = rf_te1; ew = ew_te; lfs = lfs_te;
        obase = out + (size_t)B_ * NTR_ * T_;
        N = NTE_; lbid = bid - B_ * NTR_;
    }
    int n = lbid % N;
    int b = lbid / N;

    // Per-block constants in LDS
    __shared__ float s_mux[K1_], s_muy[K1_], s_isx[K1_], s_isy[K1_], s_ck[K1_];
    __shared__ float s_sc[8];
    if (t < K1_) {
        float rfx = rf1[n * 2 + 0];
        float rfy = rf1[n * 2 + 1];
        s_mux[t] = mean1[t * 2 + 0] - rfx;
        s_muy[t] = mean1[t * 2 + 1] - rfy;
        s_isx[t] = __expf(-log_var1[t * 2 + 0]);
        s_isy[t] = __expf(-log_var1[t * 2 + 1]);
        s_ck[t]  = coeff1[t];
    }
    if (t == 0) {
        // torus: mean/rf as angle vectors, shared inverse-sigma
        float srf, crf;
        __sincosf(rf0[n], &srf, &crf);
        float sm, cm;
        __sincosf(mean0[0], &sm, &cm);
        s_sc[0] = sm - srf;              // (sin(mean) - sin(rf))
        s_sc[1] = cm - crf;              // (cos(mean) - cos(rf))
        s_sc[2] = __expf(-log_var0[0]);  // 1/exp(log_var0)
        s_sc[3] = coeff0[0];
        // softmax over the 2 ensemble weights
        float e0 = ew[n * 2 + 0], e1 = ew[n * 2 + 1];
        float mx = fmaxf(e0, e1);
        float x0 = __expf(e0 - mx), x1 = __expf(e1 - mx);
        float inv = 1.0f / (x0 + x1);
        s_sc[4] = x0 * inv;
        s_sc[5] = x1 * inv;
        s_sc[6] = __expf(lfs[n]);
    }
    __syncthreads();

    int zt = b * T_ + t;
    // torus response (K0 = 1, L0 = 1)
    float zs, zc;
    __sincosf(z0[zt], &zs, &zc);
    float ds = (zs - s_sc[0]) * s_sc[2];
    float dc = (zc - s_sc[1]) * s_sc[2];
    float dist0 = ds * ds + dc * dc;
    float r0 = __expf(__expf(-dist0) * s_sc[3]);

    // euclidean response (K1 = 16, L1 = 2)
    float2 zv = ((const float2*)z1)[zt];
    float resp = 0.0f;
#pragma unroll
    for (int k = 0; k < K1_; ++k) {
        float dx = (zv.x - s_mux[k]) * s_isx[k];
        float dy = (zv.y - s_muy[k]) * s_isy[k];
        float d = dx * dx + dy * dy;
        resp = __fmaf_rn(__expf(-d), s_ck[k], resp);
    }
    float r1 = __expf(resp);

    obase[(size_t)lbid * T_ + t] = (s_sc[4] * r0 + s_sc[5] * r1) * s_sc[6];
}

extern "C" void kernel_launch(void* const* d_in, const int* in_sizes, int n_in,
                              void* d_out, int out_size, void* d_ws, size_t ws_size,
                              hipStream_t stream) {
    const float* z0       = (const float*)d_in[0];
    const float* z1       = (const float*)d_in[1];
    const float* coeff0   = (const float*)d_in[2];
    const float* mean0    = (const float*)d_in[3];
    const float* log_var0 = (const float*)d_in[4];
    const float* coeff1   = (const float*)d_in[5];
    const float* mean1    = (const float*)d_in[6];
    const float* log_var1 = (const float*)d_in[7];
    const float* rf_tr0   = (const float*)d_in[8];
    const float* rf_tr1   = (const float*)d_in[9];
    const float* rf_te0   = (const float*)d_in[10];
    const float* rf_te1   = (const float*)d_in[11];
    const float* ew_tr    = (const float*)d_in[12];
    const float* ew_te    = (const float*)d_in[13];
    const float* lfs_tr   = (const float*)d_in[14];
    const float* lfs_te   = (const float*)d_in[15];
    float* out = (float*)d_out;

    int grid = B_ * (NTR_ + NTE_);  // 20480 blocks
    decoder_kernel<<<grid, T_, 0, stream>>>(
        z0, z1, coeff0, mean0, log_var0, coeff1, mean1, log_var1,
        rf_tr0, rf_tr1, rf_te0, rf_te1, ew_tr, ew_te, lfs_tr, lfs_te, out);
}

// Round 2
// 112.850 us; speedup vs baseline: 1.0666x; 1.0666x over previous
//
#include <hip/hip_runtime.h>
#include <math.h>

#define B_ 16
#define T_ 256
#define NTR_ 1024
#define NTE_ 256
#define K1_ 16
#define LOG2E_ 1.44269504088896340736f

// One block per receptive field n (train: 0..1023, test: 1024..1279).
// 256 threads = one t each; loop over all B=16 batches inside the block.
// Setup cost amortized 16x vs per-(b,n) blocks; k-loop constants live in
// registers across the inner b-loop (6 LDS reads per k, not per element).
__global__ __launch_bounds__(256) void decoder_kernel(
    const float* __restrict__ z0,        // (B,T,1)
    const float* __restrict__ z1,        // (B,T,2)
    const float* __restrict__ coeff0,    // (1,1)
    const float* __restrict__ mean0,     // (1,1,1)
    const float* __restrict__ log_var0,  // (1,1,1)
    const float* __restrict__ coeff1,    // (1,16)
    const float* __restrict__ mean1,     // (1,16,2)
    const float* __restrict__ log_var1,  // (1,16,2)
    const float* __restrict__ rf_tr0,    // (NTR,1)
    const float* __restrict__ rf_tr1,    // (NTR,2)
    const float* __restrict__ rf_te0,    // (NTE,1)
    const float* __restrict__ rf_te1,    // (NTE,2)
    const float* __restrict__ ew_tr,     // (NTR,2)
    const float* __restrict__ ew_te,     // (NTE,2)
    const float* __restrict__ lfs_tr,    // (NTR,)
    const float* __restrict__ lfs_te,    // (NTE,)
    float* __restrict__ out)             // out_tr (B,NTR,T) ++ out_te (B,NTE,T)
{
    const int bid = blockIdx.x;
    const int t = threadIdx.x;

    // Select train vs test ensemble (wave-uniform branch)
    const float *rf0, *rf1, *ew, *lfs;
    float* obase;
    int N, n;
    if (bid < NTR_) {
        rf0 = rf_tr0; rf1 = rf_tr1; ew = ew_tr; lfs = lfs_tr;
        obase = out;
        N = NTR_; n = bid;
    } else {
        rf0 = rf_te0; rf1 = rf_te1; ew = ew_te; lfs = lfs_te;
        obase = out + (size_t)B_ * NTR_ * T_;
        N = NTE_; n = bid - NTR_;
    }

    // Per-k euclidean constants in polynomial form with log2(e) folded in:
    //   -log2e * ((zx-mux)*ivx)^2 - log2e * ((zy-muy)*ivy)^2
    //     = zx*(ax*zx+bx) + zy*(ay*zy+by) + c
    __shared__ float s_ax[K1_], s_bx[K1_], s_ay[K1_], s_by[K1_], s_c[K1_], s_ck[K1_];
    __shared__ float s_sc[8];
    if (t < K1_) {
        float rfx = rf1[n * 2 + 0];
        float rfy = rf1[n * 2 + 1];
        float mux = mean1[t * 2 + 0] - rfx;
        float muy = mean1[t * 2 + 1] - rfy;
        float ivx = __expf(-log_var1[t * 2 + 0]);
        float ivy = __expf(-log_var1[t * 2 + 1]);
        float gx = ivx * ivx * LOG2E_;
        float gy = ivy * ivy * LOG2E_;
        s_ax[t] = -gx;
        s_bx[t] = 2.0f * gx * mux;
        s_ay[t] = -gy;
        s_by[t] = 2.0f * gy * muy;
        s_c[t]  = -gx * mux * mux - gy * muy * muy;
        s_ck[t] = coeff1[t] * LOG2E_;   // resp accumulates in log2 scale
    }
    if (t == 0) {
        // torus (K0=1,L0=1): dist0 = iv^2 * (1 - 2*(zs*s0+zc*s1) + s0^2+s1^2)
        // using sin^2+cos^2=1.  -dist0*log2e = Cn + Dn*dot.
        float srf, crf;
        __sincosf(rf0[n], &srf, &crf);
        float sm, cm;
        __sincosf(mean0[0], &sm, &cm);
        float s0 = sm - srf;
        float s1 = cm - crf;
        float iv = __expf(-log_var0[0]);
        float q = iv * iv * LOG2E_;
        s_sc[0] = s0;
        s_sc[1] = s1;
        s_sc[2] = -q * (1.0f + s0 * s0 + s1 * s1);  // Cn
        s_sc[3] = 2.0f * q;                          // Dn
        s_sc[4] = coeff0[0] * LOG2E_;                // E
        // softmax over the 2 ensemble weights, pre-scaled by exp(lfs)
        float e0 = ew[n * 2 + 0], e1 = ew[n * 2 + 1];
        float mx = fmaxf(e0, e1);
        float x0 = __expf(e0 - mx), x1 = __expf(e1 - mx);
        float elfs = __expf(lfs[n]) / (x0 + x1);
        s_sc[5] = x0 * elfs;   // w0'
        s_sc[6] = x1 * elfs;   // w1'
    }
    __syncthreads();

    // Load all B latent samples for this t (same data for every block; L2-hot)
    float zx[B_], zy[B_], resp[B_];
    const float2* z1v = (const float2*)z1;
#pragma unroll
    for (int b = 0; b < B_; ++b) {
        float2 zv = z1v[b * T_ + t];
        zx[b] = zv.x;
        zy[b] = zv.y;
        resp[b] = 0.0f;
    }

    // k-outer / b-inner: constants in registers across the 16 b-iterations
#pragma unroll
    for (int k = 0; k < K1_; ++k) {
        float ax = s_ax[k], bx = s_bx[k];
        float ay = s_ay[k], by = s_by[k];
        float c = s_c[k], ck = s_ck[k];
#pragma unroll
        for (int b = 0; b < B_; ++b) {
            float e = __fmaf_rn(zx[b], __fmaf_rn(zx[b], ax, bx),
                     __fmaf_rn(zy[b], __fmaf_rn(zy[b], ay, by), c));
            resp[b] = __fmaf_rn(__builtin_amdgcn_exp2f(e), ck, resp[b]);
        }
    }

    const float s0 = s_sc[0], s1 = s_sc[1], Cn = s_sc[2], Dn = s_sc[3];
    const float E = s_sc[4], w0p = s_sc[5], w1p = s_sc[6];

#pragma unroll
    for (int b = 0; b < B_; ++b) {
        float zs, zc;
        __sincosf(z0[b * T_ + t], &zs, &zc);
        float dot = __fmaf_rn(zc, s1, zs * s0);
        float r0 = __builtin_amdgcn_exp2f(
            __builtin_amdgcn_exp2f(__fmaf_rn(dot, Dn, Cn)) * E);
        float r1 = __builtin_amdgcn_exp2f(resp[b]);
        obase[(size_t)(b * N + n) * T_ + t] = __fmaf_rn(w0p, r0, w1p * r1);
    }
}

extern "C" void kernel_launch(void* const* d_in, const int* in_sizes, int n_in,
                              void* d_out, int out_size, void* d_ws, size_t ws_size,
                              hipStream_t stream) {
    const float* z0       = (const float*)d_in[0];
    const float* z1       = (const float*)d_in[1];
    const float* coeff0   = (const float*)d_in[2];
    const float* mean0    = (const float*)d_in[3];
    const float* log_var0 = (const float*)d_in[4];
    const float* coeff1   = (const float*)d_in[5];
    const float* mean1    = (const float*)d_in[6];
    const float* log_var1 = (const float*)d_in[7];
    const float* rf_tr0   = (const float*)d_in[8];
    const float* rf_tr1   = (const float*)d_in[9];
    const float* rf_te0   = (const float*)d_in[10];
    const float* rf_te1   = (const float*)d_in[11];
    const float* ew_tr    = (const float*)d_in[12];
    const float* ew_te    = (const float*)d_in[13];
    const float* lfs_tr   = (const float*)d_in[14];
    const float* lfs_te   = (const float*)d_in[15];
    float* out = (float*)d_out;

    int grid = NTR_ + NTE_;  // 1280 blocks, one per receptive field
    decoder_kernel<<<grid, T_, 0, stream>>>(
        z0, z1, coeff0, mean0, log_var0, coeff1, mean1, log_var1,
        rf_tr0, rf_tr1, rf_te0, rf_te1, ew_tr, ew_te, lfs_tr, lfs_te, out);
}

// Round 3
// 105.891 us; speedup vs baseline: 1.1367x; 1.0657x over previous
//
#include <hip/hip_runtime.h>
#include <math.h>

#define B_ 16
#define T_ 256
#define NTR_ 1024
#define NTE_ 256
#define K1_ 16
#define LOG2E_ 1.44269504088896340736f
#define INV2PI_ 0.15915494309189533577f

typedef __attribute__((ext_vector_type(2))) float v2f;

// One block per receptive field n (train: 0..1023, test: 1024..1279).
// 256 threads = one t each; all B=16 batches per thread, processed as 8
// b-PAIRS in 2-wide vectors so the k-loop FMAs become v_pk_fma_f32
// (double-rate), leaving v_exp_f32 as the bottleneck pipe.
// __launch_bounds__(256,5): 5 waves/SIMD -> all 5120 waves co-resident
// (exactly one round over 256 CUs).
__global__ __launch_bounds__(256, 5) void decoder_kernel(
    const float* __restrict__ z0,        // (B,T,1)
    const float* __restrict__ z1,        // (B,T,2)
    const float* __restrict__ coeff0,    // (1,1)
    const float* __restrict__ mean0,     // (1,1,1)
    const float* __restrict__ log_var0,  // (1,1,1)
    const float* __restrict__ coeff1,    // (1,16)
    const float* __restrict__ mean1,     // (1,16,2)
    const float* __restrict__ log_var1,  // (1,16,2)
    const float* __restrict__ rf_tr0,    // (NTR,1)
    const float* __restrict__ rf_tr1,    // (NTR,2)
    const float* __restrict__ rf_te0,    // (NTE,1)
    const float* __restrict__ rf_te1,    // (NTE,2)
    const float* __restrict__ ew_tr,     // (NTR,2)
    const float* __restrict__ ew_te,     // (NTE,2)
    const float* __restrict__ lfs_tr,    // (NTR,)
    const float* __restrict__ lfs_te,    // (NTE,)
    float* __restrict__ out)             // out_tr (B,NTR,T) ++ out_te (B,NTE,T)
{
    const int bid = blockIdx.x;
    const int t = threadIdx.x;

    // Select train vs test ensemble (wave-uniform branch)
    const float *rf0, *rf1, *ew, *lfs;
    float* obase;
    int N, n;
    if (bid < NTR_) {
        rf0 = rf_tr0; rf1 = rf_tr1; ew = ew_tr; lfs = lfs_tr;
        obase = out;
        N = NTR_; n = bid;
    } else {
        rf0 = rf_te0; rf1 = rf_te1; ew = ew_te; lfs = lfs_te;
        obase = out + (size_t)B_ * NTR_ * T_;
        N = NTE_; n = bid - NTR_;
    }

    // Per-k euclidean constants in polynomial form with log2(e) folded in:
    //   -log2e*((zx-mux)*ivx)^2 - log2e*((zy-muy)*ivy)^2
    //     = zx*(ax*zx+bx) + zy*(ay*zy+by) + c
    __shared__ float s_ax[K1_], s_bx[K1_], s_ay[K1_], s_by[K1_], s_c[K1_], s_ck[K1_];
    __shared__ float s_sc[8];
    if (t < K1_) {
        float rfx = rf1[n * 2 + 0];
        float rfy = rf1[n * 2 + 1];
        float mux = mean1[t * 2 + 0] - rfx;
        float muy = mean1[t * 2 + 1] - rfy;
        float ivx = __expf(-log_var1[t * 2 + 0]);
        float ivy = __expf(-log_var1[t * 2 + 1]);
        float gx = ivx * ivx * LOG2E_;
        float gy = ivy * ivy * LOG2E_;
        s_ax[t] = -gx;
        s_bx[t] = 2.0f * gx * mux;
        s_ay[t] = -gy;
        s_by[t] = 2.0f * gy * muy;
        s_c[t]  = -gx * mux * mux - gy * muy * muy;
        s_ck[t] = coeff1[t] * LOG2E_;   // resp accumulates in log2 scale
    }
    if (t == 0) {
        // torus (K0=1,L0=1): with v=(sin z,cos z), s=(sin m - sin rf, cos m - cos rf),
        // |v|^2 = 1  =>  -dist0*log2e = Cn + Dn*(v . s)
        float srf = __builtin_amdgcn_sinf(rf0[n] * INV2PI_);
        float crf = __builtin_amdgcn_cosf(rf0[n] * INV2PI_);
        float sm  = __builtin_amdgcn_sinf(mean0[0] * INV2PI_);
        float cm  = __builtin_amdgcn_cosf(mean0[0] * INV2PI_);
        float s0 = sm - srf;
        float s1 = cm - crf;
        float iv = __expf(-log_var0[0]);
        float q = iv * iv * LOG2E_;
        s_sc[0] = s0;
        s_sc[1] = s1;
        s_sc[2] = -q * (1.0f + s0 * s0 + s1 * s1);  // Cn
        s_sc[3] = 2.0f * q;                          // Dn
        s_sc[4] = coeff0[0] * LOG2E_;                // E
        // softmax over the 2 ensemble weights, pre-scaled by exp(lfs)
        float e0 = ew[n * 2 + 0], e1 = ew[n * 2 + 1];
        float mx = fmaxf(e0, e1);
        float x0 = __expf(e0 - mx), x1 = __expf(e1 - mx);
        float elfs = __expf(lfs[n]) / (x0 + x1);
        s_sc[5] = x0 * elfs;   // w0'
        s_sc[6] = x1 * elfs;   // w1'
    }
    __syncthreads();

    // Load all B latent samples for this t as 8 b-pairs (2-wide vectors).
    v2f X[B_ / 2], Y[B_ / 2], R[B_ / 2];
    const float2* z1v = (const float2*)z1;
#pragma unroll
    for (int j = 0; j < B_ / 2; ++j) {
        float2 p0 = z1v[(2 * j + 0) * T_ + t];
        float2 p1 = z1v[(2 * j + 1) * T_ + t];
        X[j] = (v2f){p0.x, p1.x};
        Y[j] = (v2f){p0.y, p1.y};
        R[j] = (v2f){0.0f, 0.0f};
    }

    // k-outer / b-pair-inner: constants in registers, FMAs in packed form
#pragma unroll
    for (int k = 0; k < K1_; ++k) {
        v2f AX = {s_ax[k], s_ax[k]};
        v2f BX = {s_bx[k], s_bx[k]};
        v2f AY = {s_ay[k], s_ay[k]};
        v2f BY = {s_by[k], s_by[k]};
        v2f Cc = {s_c[k],  s_c[k]};
        v2f CK = {s_ck[k], s_ck[k]};
#pragma unroll
        for (int j = 0; j < B_ / 2; ++j) {
            v2f e = __builtin_elementwise_fma(
                X[j], __builtin_elementwise_fma(X[j], AX, BX),
                __builtin_elementwise_fma(Y[j], __builtin_elementwise_fma(Y[j], AY, BY), Cc));
            v2f ex = {__builtin_amdgcn_exp2f(e.x), __builtin_amdgcn_exp2f(e.y)};
            R[j] = __builtin_elementwise_fma(ex, CK, R[j]);
        }
    }

    const v2f S0 = {s_sc[0], s_sc[0]};
    const v2f S1 = {s_sc[1], s_sc[1]};
    const v2f CN = {s_sc[2], s_sc[2]};
    const v2f DN = {s_sc[3], s_sc[3]};
    const float E = s_sc[4];
    const v2f W0 = {s_sc[5], s_sc[5]};
    const v2f W1 = {s_sc[6], s_sc[6]};

#pragma unroll
    for (int j = 0; j < B_ / 2; ++j) {
        float a0 = z0[(2 * j + 0) * T_ + t] * INV2PI_;
        float a1 = z0[(2 * j + 1) * T_ + t] * INV2PI_;
        v2f ZS = {__builtin_amdgcn_sinf(a0), __builtin_amdgcn_sinf(a1)};
        v2f ZC = {__builtin_amdgcn_cosf(a0), __builtin_amdgcn_cosf(a1)};
        v2f DOT = __builtin_elementwise_fma(ZC, S1, ZS * S0);
        v2f G = __builtin_elementwise_fma(DOT, DN, CN);
        v2f R0 = {__builtin_amdgcn_exp2f(__builtin_amdgcn_exp2f(G.x) * E),
                  __builtin_amdgcn_exp2f(__builtin_amdgcn_exp2f(G.y) * E)};
        v2f R1 = {__builtin_amdgcn_exp2f(R[j].x), __builtin_amdgcn_exp2f(R[j].y)};
        v2f O = __builtin_elementwise_fma(W0, R0, W1 * R1);
        obase[(size_t)((2 * j + 0) * N + n) * T_ + t] = O.x;
        obase[(size_t)((2 * j + 1) * N + n) * T_ + t] = O.y;
    }
}

extern "C" void kernel_launch(void* const* d_in, const int* in_sizes, int n_in,
                              void* d_out, int out_size, void* d_ws, size_t ws_size,
                              hipStream_t stream) {
    const float* z0       = (const float*)d_in[0];
    const float* z1       = (const float*)d_in[1];
    const float* coeff0   = (const float*)d_in[2];
    const float* mean0    = (const float*)d_in[3];
    const float* log_var0 = (const float*)d_in[4];
    const float* coeff1   = (const float*)d_in[5];
    const float* mean1    = (const float*)d_in[6];
    const float* log_var1 = (const float*)d_in[7];
    const float* rf_tr0   = (const float*)d_in[8];
    const float* rf_tr1   = (const float*)d_in[9];
    const float* rf_te0   = (const float*)d_in[10];
    const float* rf_te1   = (const float*)d_in[11];
    const float* ew_tr    = (const float*)d_in[12];
    const float* ew_te    = (const float*)d_in[13];
    const float* lfs_tr   = (const float*)d_in[14];
    const float* lfs_te   = (const float*)d_in[15];
    float* out = (float*)d_out;

    int grid = NTR_ + NTE_;  // 1280 blocks, one per receptive field
    decoder_kernel<<<grid, T_, 0, stream>>>(
        z0, z1, coeff0, mean0, log_var0, coeff1, mean1, log_var1,
        rf_tr0, rf_tr1, rf_te0, rf_te1, ew_tr, ew_te, lfs_tr, lfs_te, out);
}